// Round 18
// baseline (1468.021 us; speedup 1.0000x reference)
//
#include <hip/hip_runtime.h>

#define TT 512
#define BB 64
#define II 512
#define LL 1024
#define GROUPS 16
#define RPG 4            // batch rows per group
#define NWGS 128         // 8 pairs x 16 col-slices; each WG serves groups gp, gp+8

typedef __bf16 bf16x8 __attribute__((ext_vector_type(8)));
typedef float f32x4 __attribute__((ext_vector_type(4)));
typedef unsigned int u32x4 __attribute__((ext_vector_type(4)));

// ---------- workspace layout (bytes) ----------
// wsWi : Wi frag-ordered bf16 (xi_gemm)                          = 1 MiB
// wsWh2: Wh frag-ordered bf16 [16 w][4 wv][32 ks][64 l][8e]      = 2 MiB
// hbuf : ping-pong compact H  2 x [16 g][32 ks][4 kq][4 r][8e]   = 256 KiB
//        readiness tag = LSB of even elements of each 16B chunk
#define WSWI_OFF 0u
#define WSWH_OFF (1u << 20)
#define HBUF_OFF (3u << 20)

// global->LDS async prefetch, sc1 (aux bit4). Correctness does NOT depend on
// the aux bit: stale data fails the tag check and the sc1 register-poll
// fallback takes over.
#define GLDS16(gp_, lp_)                                                    \
  __builtin_amdgcn_global_load_lds(                                         \
      (const __attribute__((address_space(1))) void*)(const void*)(gp_),    \
      (__attribute__((address_space(3))) void*)(void*)(lp_), 16, 0, 16)

__device__ __forceinline__ unsigned short f2bf(float f) {
  unsigned int u = __builtin_bit_cast(unsigned int, f);
  u += 0x7fffu + ((u >> 16) & 1u);   // round-to-nearest-even (inputs finite)
  return (unsigned short)(u >> 16);
}

__device__ __forceinline__ bf16x8 ld_frag(const unsigned short* p) {
  return __builtin_bit_cast(bf16x8, *(const uint4*)p);
}

__device__ __forceinline__ int tagok(u32x4 a, u32x4 b, unsigned p) {
  return (int)(((a[0] & 1) == p) & ((a[1] & 1) == p) & ((a[2] & 1) == p) &
               ((a[3] & 1) == p) & ((b[0] & 1) == p) & ((b[1] & 1) == p) &
               ((b[2] & 1) == p) & ((b[3] & 1) == p));
}

// ============================================================
// prep: frag-order Wi (xi_gemm), Wh2 (scan), compact h0 (tag=0),
//       seed hbuf ping buffer 1 with tag=1 (t=1 false-positive guard).
// ============================================================
__global__ __launch_bounds__(256) void prep_kernel(
    const float* __restrict__ h0, const float* __restrict__ Wi,
    const float* __restrict__ Wh, unsigned short* __restrict__ wsWi,
    unsigned short* __restrict__ wsWh2, unsigned short* __restrict__ hbuf) {
  int idx = blockIdx.x * 256 + threadIdx.x;
  const float* src;
  unsigned short* dst;
  bool tagme = false;
  if (idx < 65536) {                       // Wi slots (for xi_gemm)
    int ln = idx & 63, s = idx >> 6;
    int nsub = s & 7, s2 = s >> 3, ks = s2 & 15, bn = s2 >> 4;
    int n = bn * 128 + nsub * 16 + (ln & 15);
    int k = ks * 32 + (ln >> 4) * 8;
    src = Wi + (size_t)n * II + k;
    dst = wsWi + (size_t)idx * 8;
  } else if (idx < 196608) {               // Wh2 slots [w:16][wv:4][ks:32][l:64]
    int o = idx - 65536;
    int l = o & 63, s = o >> 6;
    int ks = s & 31, s2 = s >> 5;
    int n4 = s2 & 3, w = s2 >> 2;
    int col = w * 64 + n4 * 16 + (l & 15);
    int k = ks * 32 + (l >> 4) * 8;
    src = Wh + (size_t)col * LL + k;
    dst = wsWh2 + (size_t)o * 8;
  } else if (idx < 204800) {               // h0 compact slots [g][ks][kq][r][8e]
    int o = idx - 196608;
    int r = o & 3, kq = (o >> 2) & 3, ks = (o >> 4) & 31, g = o >> 9;
    src = h0 + (size_t)(g * RPG + r) * LL + ks * 32 + kq * 8;
    dst = hbuf + (size_t)o * 8;
    tagme = true;
  } else if (idx < 212992) {               // seed ping buffer 1: tag = 1
    int o = idx - 204800;
    uint4 p = {0x00010001u, 0x00010001u, 0x00010001u, 0x00010001u};
    *(uint4*)(hbuf + 65536 + (size_t)o * 8) = p;
    return;
  } else {
    return;
  }
  float4 a0 = *(const float4*)src;
  float4 a1 = *(const float4*)(src + 4);
  uint4 p;
  p.x = f2bf(a0.x) | ((unsigned)f2bf(a0.y) << 16);
  p.y = f2bf(a0.z) | ((unsigned)f2bf(a0.w) << 16);
  p.z = f2bf(a1.x) | ((unsigned)f2bf(a1.y) << 16);
  p.w = f2bf(a1.z) | ((unsigned)f2bf(a1.w) << 16);
  if (tagme) {                             // h0 tag = 0 on all even elements
    p.x &= ~1u; p.y &= ~1u; p.z &= ~1u; p.w &= ~1u;
  }
  *(uint4*)dst = p;
}

// ============================================================
// xi = x @ Wi^T + bi  -> d_out (reused as xi buffer) [unchanged]
// ============================================================
__global__ __launch_bounds__(256) void xi_gemm(
    const float* __restrict__ x, const float* __restrict__ bi,
    const unsigned short* __restrict__ wsWi, float* __restrict__ out) {
  __shared__ unsigned short As[8 * 64 * 8];
  __shared__ unsigned short Bs[8 * 64 * 8];
  const int tid = threadIdx.x;
  const int ln = tid & 63;
  const int wv = tid >> 6;
  const int wm = wv >> 1, wn = wv & 1;
  const int bn = blockIdx.x;
  const int Mbase = blockIdx.y * 128;
  const int Nbase = bn * 128;

  f32x4 acc[4][4] = {};

  for (int ks = 0; ks < 16; ++ks) {
    __syncthreads();
#pragma unroll
    for (int i = 0; i < 2; ++i) {
      int slot = tid + 256 * i;
      int msub = slot >> 6;
      int l2 = slot & 63;
      const float* src =
          x + (size_t)(Mbase + msub * 16 + (l2 & 15)) * II + ks * 32 + (l2 >> 4) * 8;
      float4 a0 = *(const float4*)src;
      float4 a1 = *(const float4*)(src + 4);
      uint4 p;
      p.x = f2bf(a0.x) | ((unsigned)f2bf(a0.y) << 16);
      p.y = f2bf(a0.z) | ((unsigned)f2bf(a0.w) << 16);
      p.z = f2bf(a1.x) | ((unsigned)f2bf(a1.y) << 16);
      p.w = f2bf(a1.z) | ((unsigned)f2bf(a1.w) << 16);
      *(uint4*)(As + slot * 8) = p;
      const uint4* bsrc = (const uint4*)(wsWi + (size_t)(bn * 16 + ks) * 4096) + slot;
      *(uint4*)(Bs + slot * 8) = *bsrc;
    }
    __syncthreads();
    bf16x8 af[4];
#pragma unroll
    for (int m = 0; m < 4; ++m)
      af[m] = ld_frag(As + ((wm * 4 + m) * 64 + ln) * 8);
#pragma unroll
    for (int n = 0; n < 4; ++n) {
      bf16x8 bf = ld_frag(Bs + ((wn * 4 + n) * 64 + ln) * 8);
#pragma unroll
      for (int m = 0; m < 4; ++m)
        acc[m][n] = __builtin_amdgcn_mfma_f32_16x16x32_bf16(af[m], bf, acc[m][n], 0, 0, 0);
    }
  }
#pragma unroll
  for (int n = 0; n < 4; ++n) {
    int col = Nbase + wn * 64 + n * 16 + (ln & 15);
    float bv = bi[col];
#pragma unroll
    for (int m = 0; m < 4; ++m) {
      int row0 = Mbase + wm * 64 + m * 16 + (ln >> 4) * 4;
#pragma unroll
      for (int r = 0; r < 4; ++r)
        out[(size_t)(row0 + r) * LL + col] = acc[m][n][r] + bv;
    }
  }
}

// ============================================================
// Scan v11 — two groups per WG (g0=gp, g1=gp+8), LDS prefetch.
// Phase X: vmcnt(3) retires prefetch -> tag-validate own chunks
// in LDS -> sc1 register-poll fallback for stale lanes -> raw
// s_barrier (lgkm only; publish-ack stays off-path) -> MFMA
// (B pinned in AGPRs) -> epilogue -> prefetch other group
// (global_load_lds, no registers) -> publish h (sc1) -> out, xi.
// ============================================================
__global__ __launch_bounds__(256, 1) void scan_kernel(
    const unsigned short* __restrict__ wsWh2, float* __restrict__ out,
    unsigned short* __restrict__ hbuf) {
  __shared__ unsigned short hA[2][2][4096];   // [grp][dbuf][512 chunks x 8e] 32 KiB
  __shared__ unsigned short packb[4][64];     // per-wave pack, 128 B

  const int tid = threadIdx.x;
  const int ln = tid & 63;
  const int wv = tid >> 6;                 // 0..3 : 16-col subtile
  const int gp = blockIdx.x >> 4;          // 0..7 : pair id
  const int w = blockIdx.x & 15;           // 64-col slice
  const int g0 = gp, g1 = gp + 8;
  const int kq = ln >> 4;
  const int rdup = ln & 3;
  const int cc = ln & 15;
  const int ks_w = w * 2 + (wv >> 1);
  const int half = wv & 1;

  // ---- B-frags pinned via asm loads (32 x 16B; lands in AGPRs) ----
  u32x4 Breg[32];
  {
    const unsigned short* bsrc = wsWh2 + (size_t)(w * 4 + wv) * 16384 + ln * 8;
#pragma unroll
    for (int i = 0; i < 8; ++i) {
      const unsigned short* bp = bsrc + i * 2048;
      asm volatile(
          "global_load_dwordx4 %0, %4, off\n\t"
          "global_load_dwordx4 %1, %4, off offset:1024\n\t"
          "global_load_dwordx4 %2, %4, off offset:2048\n\t"
          "global_load_dwordx4 %3, %4, off offset:3072"
          : "=&v"(Breg[i * 4]), "=&v"(Breg[i * 4 + 1]),
            "=&v"(Breg[i * 4 + 2]), "=&v"(Breg[i * 4 + 3])
          : "v"(bp) : "memory");
    }
    asm volatile("s_waitcnt vmcnt(0)" ::: "memory");
    __builtin_amdgcn_sched_barrier(0);
  }

  const size_t ocell0 = (size_t)(g0 * RPG + kq) * LL + w * 64 + wv * 16 + cc;
  const size_t ocell1 = (size_t)(g1 * RPG + kq) * LL + w * 64 + wv * 16 + cc;

  // ---- prologue: prefetch g0@0 into hA[0][0]; xi(0) for both groups ----
  GLDS16(hbuf + g0 * 4096 + tid * 8, &hA[0][0][wv * 512]);
  GLDS16(hbuf + g0 * 4096 + (tid + 256) * 8, &hA[0][0][2048 + wv * 512]);
  float xv0n, xv1n;
  asm volatile("global_load_dword %0, %1, off"
               : "=&v"(xv0n) : "v"(out + ocell0) : "memory");
  asm volatile("global_load_dword %0, %1, off"
               : "=&v"(xv1n) : "v"(out + ocell1) : "memory");

  for (int t = 0; t < TT; ++t) {
    const unsigned ptag = (unsigned)((t >> 1) & 1);
    const unsigned ntag = (unsigned)(((t + 1) >> 1) & 1);

    // ================= PHASE A : group g0 =================
    {
      unsigned short* hw = &hA[0][t & 1][0];
      const unsigned short* hc = hbuf + (size_t)(t & 1) * 65536 + g0 * 4096;
      if (t == 0) asm volatile("s_waitcnt vmcnt(0)" ::: "memory");
      else        asm volatile("s_waitcnt vmcnt(3)" ::: "memory");
      __builtin_amdgcn_sched_barrier(0);
      u32x4 v0 = *(const u32x4*)(hw + tid * 8);
      u32x4 v1 = *(const u32x4*)(hw + (tid + 256) * 8);
      int good = tagok(v0, v1, ptag);
      if (!good) {
        do {
          asm volatile(
              "global_load_dwordx4 %0, %2, off sc1\n\t"
              "global_load_dwordx4 %1, %3, off sc1\n\t"
              "s_waitcnt vmcnt(0)"
              : "=&v"(v0), "=&v"(v1)
              : "v"(hc + tid * 8), "v"(hc + (tid + 256) * 8) : "memory");
          good = tagok(v0, v1, ptag);
        } while (!good);
        *(u32x4*)(hw + tid * 8) = v0;
        *(u32x4*)(hw + (tid + 256) * 8) = v1;
      }
      float xv = xv0n;
      asm volatile("s_waitcnt lgkmcnt(0)" ::: "memory");
      __builtin_amdgcn_s_barrier();
      asm volatile("" ::: "memory");
      __builtin_amdgcn_sched_barrier(0);

      f32x4 a0 = {}, a1 = {}, a2 = {}, a3 = {};
#pragma unroll
      for (int ks = 0; ks < 32; ks += 4) {
        bf16x8 A0 = ld_frag(hw + (ks * 16 + kq * 4 + rdup) * 8);
        bf16x8 A1 = ld_frag(hw + ((ks + 1) * 16 + kq * 4 + rdup) * 8);
        bf16x8 A2 = ld_frag(hw + ((ks + 2) * 16 + kq * 4 + rdup) * 8);
        bf16x8 A3 = ld_frag(hw + ((ks + 3) * 16 + kq * 4 + rdup) * 8);
        a0 = __builtin_amdgcn_mfma_f32_16x16x32_bf16(
            A0, __builtin_bit_cast(bf16x8, Breg[ks]), a0, 0, 0, 0);
        a1 = __builtin_amdgcn_mfma_f32_16x16x32_bf16(
            A1, __builtin_bit_cast(bf16x8, Breg[ks + 1]), a1, 0, 0, 0);
        a2 = __builtin_amdgcn_mfma_f32_16x16x32_bf16(
            A2, __builtin_bit_cast(bf16x8, Breg[ks + 2]), a2, 0, 0, 0);
        a3 = __builtin_amdgcn_mfma_f32_16x16x32_bf16(
            A3, __builtin_bit_cast(bf16x8, Breg[ks + 3]), a3, 0, 0, 0);
      }
      f32x4 s = (a0 + a1) + (a2 + a3);

      float hval = tanhf(s[kq] + xv);
      unsigned short hbf = f2bf(hval);
      if ((cc & 1) == 0) hbf = (unsigned short)((hbf & ~1u) | ntag);
      packb[wv][(cc >> 3) * 32 + kq * 8 + (cc & 7)] = hbf;
      asm volatile("s_waitcnt lgkmcnt(0)" ::: "memory");
      __builtin_amdgcn_sched_barrier(0);

      // prefetch g1@t (published one phase ago) — BEFORE publish: keeps the
      // two glds the oldest VM ops for the next phase's vmcnt(3).
      const unsigned short* pn = hbuf + (size_t)(t & 1) * 65536 + g1 * 4096;
      GLDS16(pn + tid * 8, &hA[1][t & 1][wv * 512]);
      GLDS16(pn + (tid + 256) * 8, &hA[1][t & 1][2048 + wv * 512]);

      unsigned short* hn = hbuf + (size_t)((t + 1) & 1) * 65536 + g0 * 4096;
      if (ln < 8) {
        u32x4 pk = *(const u32x4*)(&packb[wv][ln * 8]);
        asm volatile("global_store_dwordx4 %0, %1, off sc1"
                     :: "v"(hn + ks_w * 128 + half * 64 + ln * 8), "v"(pk)
                     : "memory");
      }
      out[(size_t)t * 65536 + ocell0] = hval;
      int tn = (t + 1 < TT) ? (t + 1) : t;
      asm volatile("global_load_dword %0, %1, off"
                   : "=&v"(xv0n) : "v"(out + (size_t)tn * 65536 + ocell0)
                   : "memory");
    }

    // ================= PHASE B : group g1 =================
    {
      unsigned short* hw = &hA[1][t & 1][0];
      const unsigned short* hc = hbuf + (size_t)(t & 1) * 65536 + g1 * 4096;
      asm volatile("s_waitcnt vmcnt(3)" ::: "memory");
      __builtin_amdgcn_sched_barrier(0);
      u32x4 v0 = *(const u32x4*)(hw + tid * 8);
      u32x4 v1 = *(const u32x4*)(hw + (tid + 256) * 8);
      int good = tagok(v0, v1, ptag);
      if (!good) {
        do {
          asm volatile(
              "global_load_dwordx4 %0, %2, off sc1\n\t"
              "global_load_dwordx4 %1, %3, off sc1\n\t"
              "s_waitcnt vmcnt(0)"
              : "=&v"(v0), "=&v"(v1)
              : "v"(hc + tid * 8), "v"(hc + (tid + 256) * 8) : "memory");
          good = tagok(v0, v1, ptag);
        } while (!good);
        *(u32x4*)(hw + tid * 8) = v0;
        *(u32x4*)(hw + (tid + 256) * 8) = v1;
      }
      float xv = xv1n;
      asm volatile("s_waitcnt lgkmcnt(0)" ::: "memory");
      __builtin_amdgcn_s_barrier();
      asm volatile("" ::: "memory");
      __builtin_amdgcn_sched_barrier(0);

      f32x4 a0 = {}, a1 = {}, a2 = {}, a3 = {};
#pragma unroll
      for (int ks = 0; ks < 32; ks += 4) {
        bf16x8 A0 = ld_frag(hw + (ks * 16 + kq * 4 + rdup) * 8);
        bf16x8 A1 = ld_frag(hw + ((ks + 1) * 16 + kq * 4 + rdup) * 8);
        bf16x8 A2 = ld_frag(hw + ((ks + 2) * 16 + kq * 4 + rdup) * 8);
        bf16x8 A3 = ld_frag(hw + ((ks + 3) * 16 + kq * 4 + rdup) * 8);
        a0 = __builtin_amdgcn_mfma_f32_16x16x32_bf16(
            A0, __builtin_bit_cast(bf16x8, Breg[ks]), a0, 0, 0, 0);
        a1 = __builtin_amdgcn_mfma_f32_16x16x32_bf16(
            A1, __builtin_bit_cast(bf16x8, Breg[ks + 1]), a1, 0, 0, 0);
        a2 = __builtin_amdgcn_mfma_f32_16x16x32_bf16(
            A2, __builtin_bit_cast(bf16x8, Breg[ks + 2]), a2, 0, 0, 0);
        a3 = __builtin_amdgcn_mfma_f32_16x16x32_bf16(
            A3, __builtin_bit_cast(bf16x8, Breg[ks + 3]), a3, 0, 0, 0);
      }
      f32x4 s = (a0 + a1) + (a2 + a3);

      float hval = tanhf(s[kq] + xv);
      unsigned short hbf = f2bf(hval);
      if ((cc & 1) == 0) hbf = (unsigned short)((hbf & ~1u) | ntag);
      packb[wv][(cc >> 3) * 32 + kq * 8 + (cc & 7)] = hbf;
      asm volatile("s_waitcnt lgkmcnt(0)" ::: "memory");
      __builtin_amdgcn_sched_barrier(0);

      // prefetch g0@(t+1) (published at end of phase A) — before publish.
      const unsigned short* pn = hbuf + (size_t)((t + 1) & 1) * 65536 + g0 * 4096;
      GLDS16(pn + tid * 8, &hA[0][(t + 1) & 1][wv * 512]);
      GLDS16(pn + (tid + 256) * 8, &hA[0][(t + 1) & 1][2048 + wv * 512]);

      unsigned short* hn = hbuf + (size_t)((t + 1) & 1) * 65536 + g1 * 4096;
      if (ln < 8) {
        u32x4 pk = *(const u32x4*)(&packb[wv][ln * 8]);
        asm volatile("global_store_dwordx4 %0, %1, off sc1"
                     :: "v"(hn + ks_w * 128 + half * 64 + ln * 8), "v"(pk)
                     : "memory");
      }
      out[(size_t)t * 65536 + ocell1] = hval;
      int tn = (t + 1 < TT) ? (t + 1) : t;
      asm volatile("global_load_dword %0, %1, off"
                   : "=&v"(xv1n) : "v"(out + (size_t)tn * 65536 + ocell1)
                   : "memory");
    }
  }
}

extern "C" void kernel_launch(void* const* d_in, const int* in_sizes, int n_in,
                              void* d_out, int out_size, void* d_ws, size_t ws_size,
                              hipStream_t stream) {
  const float* x  = (const float*)d_in[0];
  const float* h0 = (const float*)d_in[1];
  const float* Wi = (const float*)d_in[2];
  const float* bi = (const float*)d_in[3];
  const float* Wh = (const float*)d_in[4];
  float* out = (float*)d_out;
  char* ws = (char*)d_ws;
  unsigned short* wsWi  = (unsigned short*)(ws + WSWI_OFF);
  unsigned short* wsWh2 = (unsigned short*)(ws + WSWH_OFF);
  unsigned short* hbuf  = (unsigned short*)(ws + HBUF_OFF);

  prep_kernel<<<832, 256, 0, stream>>>(h0, Wi, Wh, wsWi, wsWh2, hbuf);
  xi_gemm<<<dim3(8, 256), 256, 0, stream>>>(x, bi, wsWi, out);
  void* args[] = {(void*)&wsWh2, (void*)&out, (void*)&hbuf};
  (void)hipLaunchCooperativeKernel(reinterpret_cast<void*>(scan_kernel),
                                   dim3(NWGS), dim3(256), args, 0, stream);
}

// Round 19
// 1069.777 us; speedup vs baseline: 1.3723x; 1.3723x over previous
//
#include <hip/hip_runtime.h>

#define TT 512
#define BB 64
#define II 512
#define LL 1024
#define GROUPS 16
#define RPG 4            // batch rows per group
#define WPG 16           // WGs per group (64 cols each)
#define NWGS (GROUPS * WPG)

typedef __bf16 bf16x8 __attribute__((ext_vector_type(8)));
typedef float f32x4 __attribute__((ext_vector_type(4)));
typedef unsigned int u32x4 __attribute__((ext_vector_type(4)));

// ---------- workspace layout (bytes) ----------
// wsWi : Wi frag-ordered bf16 (xi_gemm)                          = 1 MiB
// wsWh2: Wh frag-ordered bf16 [16 w][4 wv][32 ks][64 l][8e]      = 2 MiB
// hbuf : ping-pong compact H  2 x [16 g][32 ks][4 kq][4 r][8e]   = 256 KiB
//        readiness tag = LSB of even elements of each 16B chunk
#define WSWI_OFF 0u
#define WSWH_OFF (1u << 20)
#define HBUF_OFF (3u << 20)

__device__ __forceinline__ unsigned short f2bf(float f) {
  unsigned int u = __builtin_bit_cast(unsigned int, f);
  u += 0x7fffu + ((u >> 16) & 1u);   // round-to-nearest-even (inputs finite)
  return (unsigned short)(u >> 16);
}

__device__ __forceinline__ bf16x8 ld_frag(const unsigned short* p) {
  return __builtin_bit_cast(bf16x8, *(const uint4*)p);
}

// ============================================================
// prep: frag-order Wi (xi_gemm), Wh2 (scan), compact h0 (tag=0),
//       seed hbuf ping buffer 1 with tag=1 (t=1 false-positive guard).
// ============================================================
__global__ __launch_bounds__(256) void prep_kernel(
    const float* __restrict__ h0, const float* __restrict__ Wi,
    const float* __restrict__ Wh, unsigned short* __restrict__ wsWi,
    unsigned short* __restrict__ wsWh2, unsigned short* __restrict__ hbuf) {
  int idx = blockIdx.x * 256 + threadIdx.x;
  const float* src;
  unsigned short* dst;
  bool tagme = false;
  if (idx < 65536) {                       // Wi slots (for xi_gemm)
    int ln = idx & 63, s = idx >> 6;
    int nsub = s & 7, s2 = s >> 3, ks = s2 & 15, bn = s2 >> 4;
    int n = bn * 128 + nsub * 16 + (ln & 15);
    int k = ks * 32 + (ln >> 4) * 8;
    src = Wi + (size_t)n * II + k;
    dst = wsWi + (size_t)idx * 8;
  } else if (idx < 196608) {               // Wh2 slots [w:16][wv:4][ks:32][l:64]
    int o = idx - 65536;
    int l = o & 63, s = o >> 6;
    int ks = s & 31, s2 = s >> 5;
    int n4 = s2 & 3, w = s2 >> 2;
    int col = w * 64 + n4 * 16 + (l & 15);
    int k = ks * 32 + (l >> 4) * 8;
    src = Wh + (size_t)col * LL + k;
    dst = wsWh2 + (size_t)o * 8;
  } else if (idx < 204800) {               // h0 compact slots [g][ks][kq][r][8e]
    int o = idx - 196608;
    int r = o & 3, kq = (o >> 2) & 3, ks = (o >> 4) & 31, g = o >> 9;
    src = h0 + (size_t)(g * RPG + r) * LL + ks * 32 + kq * 8;
    dst = hbuf + (size_t)o * 8;
    tagme = true;
  } else if (idx < 212992) {               // seed ping buffer 1: tag = 1
    int o = idx - 204800;
    uint4 p = {0x00010001u, 0x00010001u, 0x00010001u, 0x00010001u};
    *(uint4*)(hbuf + 65536 + (size_t)o * 8) = p;
    return;
  } else {
    return;
  }
  float4 a0 = *(const float4*)src;
  float4 a1 = *(const float4*)(src + 4);
  uint4 p;
  p.x = f2bf(a0.x) | ((unsigned)f2bf(a0.y) << 16);
  p.y = f2bf(a0.z) | ((unsigned)f2bf(a0.w) << 16);
  p.z = f2bf(a1.x) | ((unsigned)f2bf(a1.y) << 16);
  p.w = f2bf(a1.z) | ((unsigned)f2bf(a1.w) << 16);
  if (tagme) {                             // h0 tag = 0 on all even elements
    p.x &= ~1u; p.y &= ~1u; p.z &= ~1u; p.w &= ~1u;
  }
  *(uint4*)dst = p;
}

// ============================================================
// xi = x @ Wi^T + bi  -> d_out (reused as xi buffer) [unchanged]
// ============================================================
__global__ __launch_bounds__(256) void xi_gemm(
    const float* __restrict__ x, const float* __restrict__ bi,
    const unsigned short* __restrict__ wsWi, float* __restrict__ out) {
  __shared__ unsigned short As[8 * 64 * 8];
  __shared__ unsigned short Bs[8 * 64 * 8];
  const int tid = threadIdx.x;
  const int ln = tid & 63;
  const int wv = tid >> 6;
  const int wm = wv >> 1, wn = wv & 1;
  const int bn = blockIdx.x;
  const int Mbase = blockIdx.y * 128;
  const int Nbase = bn * 128;

  f32x4 acc[4][4] = {};

  for (int ks = 0; ks < 16; ++ks) {
    __syncthreads();
#pragma unroll
    for (int i = 0; i < 2; ++i) {
      int slot = tid + 256 * i;
      int msub = slot >> 6;
      int l2 = slot & 63;
      const float* src =
          x + (size_t)(Mbase + msub * 16 + (l2 & 15)) * II + ks * 32 + (l2 >> 4) * 8;
      float4 a0 = *(const float4*)src;
      float4 a1 = *(const float4*)(src + 4);
      uint4 p;
      p.x = f2bf(a0.x) | ((unsigned)f2bf(a0.y) << 16);
      p.y = f2bf(a0.z) | ((unsigned)f2bf(a0.w) << 16);
      p.z = f2bf(a1.x) | ((unsigned)f2bf(a1.y) << 16);
      p.w = f2bf(a1.z) | ((unsigned)f2bf(a1.w) << 16);
      *(uint4*)(As + slot * 8) = p;
      const uint4* bsrc = (const uint4*)(wsWi + (size_t)(bn * 16 + ks) * 4096) + slot;
      *(uint4*)(Bs + slot * 8) = *bsrc;
    }
    __syncthreads();
    bf16x8 af[4];
#pragma unroll
    for (int m = 0; m < 4; ++m)
      af[m] = ld_frag(As + ((wm * 4 + m) * 64 + ln) * 8);
#pragma unroll
    for (int n = 0; n < 4; ++n) {
      bf16x8 bf = ld_frag(Bs + ((wn * 4 + n) * 64 + ln) * 8);
#pragma unroll
      for (int m = 0; m < 4; ++m)
        acc[m][n] = __builtin_amdgcn_mfma_f32_16x16x32_bf16(af[m], bf, acc[m][n], 0, 0, 0);
    }
  }
#pragma unroll
  for (int n = 0; n < 4; ++n) {
    int col = Nbase + wn * 64 + n * 16 + (ln & 15);
    float bv = bi[col];
#pragma unroll
    for (int m = 0; m < 4; ++m) {
      int row0 = Mbase + wm * 64 + m * 16 + (ln >> 4) * 4;
#pragma unroll
      for (int r = 0; r < 4; ++r)
        out[(size_t)(row0 + r) * LL + col] = acc[m][n][r] + bv;
    }
  }
}

// ============================================================
// Batch-grouped persistent scan v8 (r15, best) — flagless
// data-tagged protocol + B pinned in AGPRs via asm loads.
// 16 groups x 4 rows; 16 WGs/group x 4 waves (64 cols/WG).
// Per step (~1.86 us = structural L3-RT floor): poll-gather own
// 2 chunks (sc1, tag-in-LSB) -> LDS dbuf -> ONE barrier -> 32
// MFMA (A broadcast from LDS, B in AGPRs) -> all-lane tanh ->
// publish h (sc1, no drain, no flag) -> out + xi prefetch.
// ============================================================
__global__ __launch_bounds__(256, 1) void scan_kernel(
    const unsigned short* __restrict__ wsWh2, float* __restrict__ out,
    unsigned short* __restrict__ hbuf) {
  __shared__ unsigned short hA[2][4096];      // 2 x 8 KiB compact H
  __shared__ unsigned short packb[4][64];     // per-wave pack, 128 B each

  const int tid = threadIdx.x;
  const int ln = tid & 63;
  const int wv = tid >> 6;                 // 0..3 : 16-col subtile
  const int g = blockIdx.x >> 4;           // group
  const int w = blockIdx.x & 15;           // 64-col slice within group
  const int kq = ln >> 4;                  // batch row this lane owns
  const int rdup = ln & 3;
  const int cc = ln & 15;                  // col within wave's 16
  const int ks_w = w * 2 + (wv >> 1);      // wave's compact-h ks slot
  const int half = wv & 1;

  // ---- B-frags pinned via asm loads (32 x 16B; lands in AGPRs) ----
  u32x4 Breg[32];
  {
    const unsigned short* bsrc = wsWh2 + (size_t)(w * 4 + wv) * 16384 + ln * 8;
#pragma unroll
    for (int i = 0; i < 8; ++i) {
      const unsigned short* bp = bsrc + i * 2048;   // 4 ks per iter (4 KB)
      asm volatile(
          "global_load_dwordx4 %0, %4, off\n\t"
          "global_load_dwordx4 %1, %4, off offset:1024\n\t"
          "global_load_dwordx4 %2, %4, off offset:2048\n\t"
          "global_load_dwordx4 %3, %4, off offset:3072"
          : "=&v"(Breg[i * 4]), "=&v"(Breg[i * 4 + 1]),
            "=&v"(Breg[i * 4 + 2]), "=&v"(Breg[i * 4 + 3])
          : "v"(bp) : "memory");
    }
    asm volatile("s_waitcnt vmcnt(0)" ::: "memory");
    __builtin_amdgcn_sched_barrier(0);
  }

  const int c0 = tid, c1 = tid + 256;      // this thread's two 16B chunks

  // my output cell (row kq of group, col w*64+wv*16+cc); also my xi address
  const size_t ocell = (size_t)(g * RPG + kq) * LL + w * 64 + wv * 16 + cc;

  // ---- prologue: prefetch xi(0) ----
  float xv_next;
  asm volatile("global_load_dword %0, %1, off"
               : "=&v"(xv_next) : "v"(out + ocell) : "memory");

  for (int t = 0; t < TT; ++t) {
    const unsigned ptag = (unsigned)((t >> 1) & 1);        // expected tag
    const unsigned ntag = (unsigned)(((t + 1) >> 1) & 1);  // tag for h_{t+1}

    // ---- poll-gather: re-load own 2 chunks until all 8 tags match ----
    const unsigned short* hcur = hbuf + (size_t)(t & 1) * 65536 + g * 4096;
    const unsigned short* p0 = hcur + c0 * 8;
    const unsigned short* p1 = hcur + c1 * 8;
    u32x4 hv0, hv1;
    {
      int good;
      do {
        asm volatile(
            "global_load_dwordx4 %0, %2, off sc1\n\t"
            "global_load_dwordx4 %1, %3, off sc1\n\t"
            "s_waitcnt vmcnt(0)"
            : "=&v"(hv0), "=&v"(hv1) : "v"(p0), "v"(p1) : "memory");
        good = ((hv0[0] & 1) == ptag) & ((hv0[1] & 1) == ptag) &
               ((hv0[2] & 1) == ptag) & ((hv0[3] & 1) == ptag) &
               ((hv1[0] & 1) == ptag) & ((hv1[1] & 1) == ptag) &
               ((hv1[2] & 1) == ptag) & ((hv1[3] & 1) == ptag);
      } while (__all(good) == 0);
    }
    __builtin_amdgcn_sched_barrier(0);
    unsigned short* hw = hA[t & 1];
    *(u32x4*)(hw + c0 * 8) = hv0;
    *(u32x4*)(hw + c1 * 8) = hv1;
    float xv = xv_next;                    // xi landed under the poll
    __syncthreads();                       // the ONE block barrier per step

    // ---- MFMA: K=1024, A from LDS (broadcast reads), B in AGPRs ----
    f32x4 a0 = {}, a1 = {}, a2 = {}, a3 = {};
#pragma unroll
    for (int ks = 0; ks < 32; ks += 4) {
      bf16x8 A0 = ld_frag(hw + (ks * 16 + kq * 4 + rdup) * 8);
      bf16x8 A1 = ld_frag(hw + ((ks + 1) * 16 + kq * 4 + rdup) * 8);
      bf16x8 A2 = ld_frag(hw + ((ks + 2) * 16 + kq * 4 + rdup) * 8);
      bf16x8 A3 = ld_frag(hw + ((ks + 3) * 16 + kq * 4 + rdup) * 8);
      a0 = __builtin_amdgcn_mfma_f32_16x16x32_bf16(
          A0, __builtin_bit_cast(bf16x8, Breg[ks]), a0, 0, 0, 0);
      a1 = __builtin_amdgcn_mfma_f32_16x16x32_bf16(
          A1, __builtin_bit_cast(bf16x8, Breg[ks + 1]), a1, 0, 0, 0);
      a2 = __builtin_amdgcn_mfma_f32_16x16x32_bf16(
          A2, __builtin_bit_cast(bf16x8, Breg[ks + 2]), a2, 0, 0, 0);
      a3 = __builtin_amdgcn_mfma_f32_16x16x32_bf16(
          A3, __builtin_bit_cast(bf16x8, Breg[ks + 3]), a3, 0, 0, 0);
    }
    f32x4 s = (a0 + a1) + (a2 + a3);

    // ---- all-lane epilogue: lane owns (row kq, col cc) ----
    float hval = tanhf(s[kq] + xv);
    unsigned short hbf = f2bf(hval);
    if ((cc & 1) == 0)                     // even elements carry the tag
      hbf = (unsigned short)((hbf & ~1u) | ntag);
    packb[wv][(cc >> 3) * 32 + kq * 8 + (cc & 7)] = hbf;
    asm volatile("s_waitcnt lgkmcnt(0)" ::: "memory");
    __builtin_amdgcn_sched_barrier(0);

    // ---- publish h (sc1) — no drain, no flag; then out + xi(t+1) ----
    unsigned short* hnext = hbuf + (size_t)((t + 1) & 1) * 65536 + g * 4096;
    if (ln < 8) {
      u32x4 pk = *(const u32x4*)(&packb[wv][ln * 8]);
      unsigned short* dp = hnext + ks_w * 128 + half * 64 + ln * 8;
      asm volatile("global_store_dwordx4 %0, %1, off sc1"
                   :: "v"(dp), "v"(pk) : "memory");
    }
    out[(size_t)t * 65536 + ocell] = hval;
    {
      int tn = (t + 1 < TT) ? (t + 1) : t;
      asm volatile("global_load_dword %0, %1, off"
                   : "=&v"(xv_next) : "v"(out + (size_t)tn * 65536 + ocell)
                   : "memory");
    }
  }
}

extern "C" void kernel_launch(void* const* d_in, const int* in_sizes, int n_in,
                              void* d_out, int out_size, void* d_ws, size_t ws_size,
                              hipStream_t stream) {
  const float* x  = (const float*)d_in[0];
  const float* h0 = (const float*)d_in[1];
  const float* Wi = (const float*)d_in[2];
  const float* bi = (const float*)d_in[3];
  const float* Wh = (const float*)d_in[4];
  float* out = (float*)d_out;
  char* ws = (char*)d_ws;
  unsigned short* wsWi  = (unsigned short*)(ws + WSWI_OFF);
  unsigned short* wsWh2 = (unsigned short*)(ws + WSWH_OFF);
  unsigned short* hbuf  = (unsigned short*)(ws + HBUF_OFF);

  prep_kernel<<<832, 256, 0, stream>>>(h0, Wi, Wh, wsWi, wsWh2, hbuf);
  xi_gemm<<<dim3(8, 256), 256, 0, stream>>>(x, bi, wsWi, out);
  void* args[] = {(void*)&wsWh2, (void*)&out, (void*)&hbuf};
  (void)hipLaunchCooperativeKernel(reinterpret_cast<void*>(scan_kernel),
                                   dim3(NWGS), dim3(256), args, 0, stream);
}